// Round 10
// baseline (204.211 us; speedup 1.0000x reference)
//
#include <hip/hip_runtime.h>
#include <hip/hip_bf16.h>
#include <math.h>

// B=4, L=S=2048, H=8, E=64, T=1.0.  I/O fp32.
// Pipeline: tr_fwd (transpose -> bf16 [tensor,bh,e][t]; first 5 blocks also
// build twiddle/combine tables in ws) -> fft_fwd (real-packed 1024-pt radix-4
// FFT, register-fused stage pairs, 2 series/block, PADded LDS; Q plane
// pre-scaled 0.125*log2e; V plane chunk-swizzled) -> flash_mfma (8-wave
// 128-row blocks; Q frags strided from Pq; K reg-staged from Pk + in-flash
// transpose ds_write into swizzled Ks; V via global_load_lds; counted
// vmcnt(2)/vmcnt(1), raw s_barrier, setprio, cvt_pk, NH=4 y-split)
// -> fft_inv (register-fused) -> out_tr.
// R18: qkpack ELIMINATED (34.6 MB HBM round-trip + 1 launch). flash consumes
// Pq/Pk planes directly; K transpose done in-flash (lane loads dwordx4 of one
// chan row, scatters 8 ds_write_b16; y&7==j makes write swizzle match the
// unchanged read-side kco swizzle). numb moves to [3PL,7PL); st aliases 0.
#define LOGN  11
#define NN    2048
#define LOGM  10
#define MM    1024
#define NF    1025
#define NYP   1056         // NF padded to 33 tiles of 32 (pads zeroed)
#define TWO_PI 6.283185307179586f
#define INV_SQRT_N 0.022097086912079608f      // 1/sqrt(2048)
#define INV_SCALE  0.044194173824159216f      // 2/sqrt(2048)  (M*z -> out)
#define LOG2E      1.4426950408889634f

#define PAD(i) ((i) + ((i) >> 4))
#define MMP   1088          // PAD(1023)+1
#define TWP   816           // PAD(767)+1

typedef __attribute__((ext_vector_type(8))) short bhalf8;
typedef __attribute__((ext_vector_type(4))) float f32x4;

#define MFMA16(a, b, c) __builtin_amdgcn_mfma_f32_16x16x32_bf16(a, b, c, 0, 0, 0)

#define GLD16(gp, lp)                                                              \
    __builtin_amdgcn_global_load_lds(                                              \
        (const __attribute__((address_space(1))) void*)(gp),                       \
        (__attribute__((address_space(3))) void*)(lp), 16, 0, 0)

#define CVTPK(dst, lo, hi) \
    asm("v_cvt_pk_bf16_f32 %0, %1, %2" : "=v"(dst) : "v"(lo), "v"(hi))

#define EXP2F(dst, src) \
    asm("v_exp_f32 %0, %1" : "=v"(dst) : "v"(src))

__device__ __forceinline__ unsigned short f2bf(float f) {
    union { float f; unsigned u; } v; v.f = f;
    unsigned r = v.u + 0x7FFFu + ((v.u >> 16) & 1u);   // RNE
    return (unsigned short)(r >> 16);
}
__device__ __forceinline__ float bf2f(unsigned short h) {
    union { unsigned u; float f; } v; v.u = ((unsigned)h) << 16;
    return v.f;
}

__device__ __forceinline__ float2 cmul(float2 x, float2 w) {
    return make_float2(x.x * w.x - x.y * w.y, x.x * w.y + x.y * w.x);
}

// radix-4 butterfly in place (members already twiddled).  fwd: -j on y1.
template<bool FWD>
__device__ __forceinline__ void r4(float2& a, float2& b, float2& c, float2& d) {
    float2 apc = make_float2(a.x + c.x, a.y + c.y);
    float2 amc = make_float2(a.x - c.x, a.y - c.y);
    float2 bpd = make_float2(b.x + d.x, b.y + d.y);
    float2 bmd = make_float2(b.x - d.x, b.y - d.y);
    a = make_float2(apc.x + bpd.x, apc.y + bpd.y);
    c = make_float2(apc.x - bpd.x, apc.y - bpd.y);
    if (FWD) {
        b = make_float2(amc.x + bmd.y, amc.y - bmd.x);
        d = make_float2(amc.x - bmd.y, amc.y + bmd.x);
    } else {
        b = make_float2(amc.x - bmd.y, amc.y + bmd.x);
        d = make_float2(amc.x + bmd.y, amc.y - bmd.x);
    }
}

// s0+s1 on 16 register points x[k], k = 4i+c <-> pos 16G+4c+i.
template<bool FWD>
__device__ __forceinline__ void s0s1(float2 x[16], const float2* tw) {
    #pragma unroll
    for (int c = 0; c < 4; c++)                 // s0: over i, twiddle-free
        r4<FWD>(x[c], x[4 + c], x[8 + c], x[12 + c]);
    #pragma unroll
    for (int i = 0; i < 4; i++) {               // s1: over c, e = 64i
        float2 w1 = tw[PAD(64 * i)], w2 = tw[PAD(128 * i)], w3 = tw[PAD(192 * i)];
        x[4 * i + 1] = cmul(x[4 * i + 1], w1);
        x[4 * i + 2] = cmul(x[4 * i + 2], w2);
        x[4 * i + 3] = cmul(x[4 * i + 3], w3);
        r4<FWD>(x[4 * i], x[4 * i + 1], x[4 * i + 2], x[4 * i + 3]);
    }
}

// s2+s3 fused (one LDS RW) then s4 (one LDS RW).  Thread param (q,r).
// Caller must barrier before (s0s1 writes) — this fn barriers internally.
template<bool FWD>
__device__ __forceinline__ void fft_mid(float2* bufS, const float2* tw, int q, int r)
{
    {   // s2 (e=16r, over c) + s3 (e=4(16c+r), over d)
        float2 v[4][4];   // v[d][c] = buf[256q + 64d + 16c + r]
        #pragma unroll
        for (int d = 0; d < 4; d++)
            #pragma unroll
            for (int c = 0; c < 4; c++)
                v[d][c] = bufS[PAD(256 * q + 64 * d + 16 * c + r)];
        float2 w1 = tw[PAD(16 * r)], w2 = tw[PAD(32 * r)], w3 = tw[PAD(48 * r)];
        #pragma unroll
        for (int d = 0; d < 4; d++) {
            v[d][1] = cmul(v[d][1], w1);
            v[d][2] = cmul(v[d][2], w2);
            v[d][3] = cmul(v[d][3], w3);
            r4<FWD>(v[d][0], v[d][1], v[d][2], v[d][3]);
        }
        #pragma unroll
        for (int c = 0; c < 4; c++) {
            int e = 4 * (16 * c + r);
            float2 u1 = tw[PAD(e)], u2 = tw[PAD(2 * e)], u3 = tw[PAD(3 * e)];
            v[1][c] = cmul(v[1][c], u1);
            v[2][c] = cmul(v[2][c], u2);
            v[3][c] = cmul(v[3][c], u3);
            r4<FWD>(v[0][c], v[1][c], v[2][c], v[3][c]);
        }
        #pragma unroll
        for (int d = 0; d < 4; d++)
            #pragma unroll
            for (int c = 0; c < 4; c++)
                bufS[PAD(256 * q + 64 * d + 16 * c + r)] = v[d][c];
    }
    __syncthreads();
    {   // s4: 4 groups per thread, p4 = 16q + r + 64k, e = p4
        #pragma unroll
        for (int k = 0; k < 4; k++) {
            int p4 = 16 * q + r + 64 * k;
            float2 a = bufS[PAD(p4)];
            float2 b = bufS[PAD(p4 + 256)];
            float2 c = bufS[PAD(p4 + 512)];
            float2 d = bufS[PAD(p4 + 768)];
            b = cmul(b, tw[PAD(p4)]);
            c = cmul(c, tw[PAD(2 * p4)]);
            d = cmul(d, tw[PAD(3 * p4)]);
            r4<FWD>(a, b, c, d);
            bufS[PAD(p4)]       = a;
            bufS[PAD(p4 + 256)] = b;
            bufS[PAD(p4 + 512)] = c;
            bufS[PAD(p4 + 768)] = d;
        }
    }
    __syncthreads();
}

// ---------------------------------------------------------------------------
// Input transpose: in[b][t][h][e] fp32 -> ttr[(tensor*32+bh)*64+e][t] bf16.
// 64x64 tiles via LDS; both global sides fully coalesced; packed u32x2 stores.
// First 5 (y==0,z==0) blocks also build the twiddle/combine tables.
// ---------------------------------------------------------------------------
__global__ __launch_bounds__(256) void tr_fwd(const float* __restrict__ q,
                                              const float* __restrict__ k,
                                              const float* __restrict__ v,
                                              unsigned short* __restrict__ ttr,
                                              float2* __restrict__ twf,
                                              float2* __restrict__ twi,
                                              float2* __restrict__ rc)
{
    __shared__ float Ts[64][65];
    int tt     = blockIdx.x;          // t-tile 0..31
    int h      = blockIdx.y;          // 0..7
    int z      = blockIdx.z;          // tensor*4 + b
    int tensor = z >> 2;
    int b      = z & 3;
    int tid    = threadIdx.x;
    int t0     = tt * 64;

    if (z == 0 && h == 0 && tt < 5) {          // table gen (once per launch)
        int i = tt * 256 + tid;
        if (i < 768) {
            float ang = TWO_PI * (float)i / (float)MM;
            float sv, cv;
            __sincosf(ang, &sv, &cv);
            twf[i] = make_float2(cv, -sv);
            twi[i] = make_float2(cv,  sv);
        }
        if (i < 1025) {
            float ang = TWO_PI * (float)i / (float)NN;
            float sv, cv;
            __sincosf(ang, &sv, &cv);
            rc[i] = make_float2(cv, sv);
        }
    }

    const float* in = (tensor == 0) ? q : (tensor == 1) ? k : v;

    {
        int tl = tid >> 2, ec = (tid & 3) * 16;
        const float* src = in + ((size_t)b * 2048 + t0 + tl) * 512 + h * 64 + ec;
        #pragma unroll
        for (int m = 0; m < 4; m++) {
            float4 v4 = *(const float4*)(src + m * 4);
            Ts[tl][ec + m * 4 + 0] = v4.x;
            Ts[tl][ec + m * 4 + 1] = v4.y;
            Ts[tl][ec + m * 4 + 2] = v4.z;
            Ts[tl][ec + m * 4 + 3] = v4.w;
        }
    }
    __syncthreads();
    {
        int el = tid >> 2, tc = (tid & 3) * 16;
        size_t row = ((size_t)(tensor * 32 + b * 8 + h)) * 64 + el;
        unsigned short* dst = ttr + row * 2048 + t0 + tc;
        #pragma unroll
        for (int m = 0; m < 4; m++) {
            float a0 = Ts[tc + m * 4 + 0][el], a1 = Ts[tc + m * 4 + 1][el];
            float a2 = Ts[tc + m * 4 + 2][el], a3 = Ts[tc + m * 4 + 3][el];
            unsigned u0, u1;
            CVTPK(u0, a0, a1);
            CVTPK(u1, a2, a3);
            uint2 o; o.x = u0; o.y = u1;
            *(uint2*)(dst + m * 4) = o;
        }
    }
}

// ---------------------------------------------------------------------------
// Forward rFFT (ortho), 2 series per 128-thread block (wave = series).
// Register-fused load+s0+s1; thread m loads inputs {m+64k} (coalesced).
// Output bf16 planes P[bh*128+kk][1056]; Q plane carries 0.125*log2e.
// V plane: 8-elem chunks stored at chunk ^ ((row>>2)&3).
// ---------------------------------------------------------------------------
__global__ __launch_bounds__(128) void fft_fwd(const unsigned short* __restrict__ ttr,
                                               const float2* __restrict__ twg,
                                               const float2* __restrict__ rc,
                                               unsigned short* __restrict__ Pq,
                                               unsigned short* __restrict__ Pk,
                                               unsigned short* __restrict__ Pv)
{
    __shared__ float2 buf[2][MMP];
    __shared__ float2 tw[TWP];

    int g  = blockIdx.x;              // 0..3071
    int t  = threadIdx.x;
    int w  = t >> 6, tp = t & 63;
    int q4 = tp >> 4, r = tp & 15;
    int G  = ((tp & 3) << 4) | (tp & 12) | (tp >> 4);   // rev3(tp)

    int s      = 2 * g + w;
    int p      = s % 96;              // tensor*32 + bh
    int e      = s / 96;              // 0..63
    int tensor = p / 32;
    int bh     = p % 32;

    unsigned short* plane = (tensor == 0) ? Pq : (tensor == 1) ? Pk : Pv;
    float scl = (tensor == 0) ? (INV_SQRT_N * 0.125f * LOG2E) : INV_SQRT_N;
    int vk3 = (tensor == 2) ? (((e >> 2) & 3) << 3) : 0;
    unsigned short* dre  = plane + ((size_t)bh * 128 + e) * NYP;
    unsigned short* dim_ = dre + (size_t)64 * NYP;
    const unsigned short* src = ttr + ((size_t)p * 64 + e) * 2048;

    #pragma unroll
    for (int i = t; i < 768; i += 128) tw[PAD(i)] = twg[i];

    float2* bufS = buf[w];

    // ---- load + s0 + s1 in registers ----
    float2 x[16];
    #pragma unroll
    for (int k = 0; k < 16; k++) {
        unsigned pr = *(const unsigned*)(src + 2 * (tp + 64 * k));
        x[k] = make_float2(bf2f((unsigned short)(pr & 0xFFFFu)),
                           bf2f((unsigned short)(pr >> 16)));
    }
    s0s1<true>(x, tw);
    #pragma unroll
    for (int k = 0; k < 16; k++)
        bufS[PAD(16 * G + 4 * (k & 3) + (k >> 2))] = x[k];
    __syncthreads();

    fft_mid<true>(bufS, tw, q4, r);

    // fwd combine uses (cs,sn) = (rc.x, -rc.y):
#define RPOINT(Ai, Bi, CX, CY, XR, XI) do {                                \
        float Ex = 0.5f * (Ai.x + Bi.x), Ey = 0.5f * (Ai.y - Bi.y);        \
        float Dx = 0.5f * (Ai.x - Bi.x), Dy = 0.5f * (Ai.y + Bi.y);        \
        float Ox = Dy, Oy = -Dx;                                           \
        XR = (Ex + (CX) * Ox + (CY) * Oy) * scl;                           \
        XI = (Ey + (CX) * Oy - (CY) * Ox) * scl;                           \
    } while (0)

    #pragma unroll
    for (int i = 0; i < 8; i++) {
        int kk = 2 * tp + 128 * i;                   // even, 0..1022
        float2 A0 = bufS[PAD(kk)];
        float2 B0 = bufS[PAD((MM - kk) & (MM - 1))];
        float2 A1 = bufS[PAD(kk + 1)];
        float2 B1 = bufS[PAD(MM - kk - 1)];
        float4 rq = *(const float4*)(&rc[kk]);       // (c0,s0,c1,s1)
        float Xr0, Xi0, Xr1, Xi1;
        RPOINT(A0, B0, rq.x, rq.y, Xr0, Xi0);
        RPOINT(A1, B1, rq.z, rq.w, Xr1, Xi1);
        unsigned ur, ui;
        CVTPK(ur, Xr0, Xr1);
        CVTPK(ui, Xi0, Xi1);
        int ks = kk ^ vk3;                           // swizzle stays even
        *(unsigned*)(dre + ks)  = ur;
        *(unsigned*)(dim_ + ks) = ui;
    }
    // tail: kk = 1024 (cs=-1, sn=0) + zero pads 1025..1055
    if (tp < 16) {
        unsigned ur = 0, ui = 0;
        if (tp == 0) {
            float2 A = bufS[PAD(0)];                  // A == Bc at kk=1024
            float Xr = (A.x - A.y) * scl;             // Ex + (-1)*Ox
            float zz = 0.f;
            CVTPK(ur, Xr, zz);
        }
        int ks = (1024 + 2 * tp) ^ vk3;
        *(unsigned*)(dre + ks)  = ur;
        *(unsigned*)(dim_ + ks) = ui;
    }
#undef RPOINT
}

// ---------------------------------------------------------------------------
// MFMA flash attention, no-max softmax, y-split xNH, XCD swizzle.
// 8-wave 128-row blocks; Q frags strided direct from Pq; K reg-staged from Pk
// with in-flash transpose ds_write (chunk ^ (y&7) swizzle, y&7 == j so the
// read-side kco is unchanged); V via global_load_lds.  Counted waits:
// top vmcnt(2) (V[cur] done), bottom vmcnt(1) (K regs landed) -> ds_write.
// numb partial planes: [h][bh][kk=0..127][x=0..1055] bf16 at nb0/nb1.
// ---------------------------------------------------------------------------
struct FlashShared {
    union {
        struct {
            unsigned short Ks[2][32][128];   // 16 KB, chunk-XOR-swizzled rows
            unsigned short Vs[2][128][32];   // 16 KB, chunk-swizzled (fft_fwd)
        } kv;                                // 32 KB
        unsigned short OutT[128][136];       // 34 KB (epilogue only)
    } u;
    unsigned short Ps[8][16][40];            // 10 KB, wave-private
};

template<int NH>
__global__ __launch_bounds__(512) void flash_mfma(
    const unsigned short* __restrict__ Pq,   // [bh*128+chan][1056] bf16 (scaled)
    const unsigned short* __restrict__ Pk,   // [bh*128+chan][1056] bf16
    const unsigned short* __restrict__ Vt,   // [bh*128+kk][1056] bf16, swizzled
    unsigned short* __restrict__ nb0,        // partial planes 0,1
    unsigned short* __restrict__ nb1,        // partial planes 2,3 (NH=4)
    float* __restrict__ lbuf)                // [NH][bh*1056+x] fp32
{
    __shared__ FlashShared S;

    int g    = blockIdx.x;            // idx*32 + bh : g%8 == bh%8 (XCD pin)
    int bh   = g & 31;
    int idx  = g >> 5;                // 0..9*NH-1
    int half = idx / 9;               // y-quarter (or y-half)
    int x0   = (idx % 9) * 128;       // x-tile base (128 rows)
    int tid  = threadIdx.x;
    int w    = tid >> 6;              // 0..7
    int lane = tid & 63;
    int qd   = lane >> 4;
    int col  = lane & 15;

    // ---- Q A-fragments: strided loads from Pq plane + sign trick ----
    int xrow = x0 + w * 16 + col;
    int xq   = min(xrow, 1024);
    const unsigned short* qbase = Pq + (size_t)bh * 128 * NYP + xq;
    bhalf8 Are[4], Aim[4];
    #pragma unroll
    for (int ks = 0; ks < 4; ks++) {
        bhalf8 a;
        #pragma unroll
        for (int j = 0; j < 8; j++)
            a[j] = (short)qbase[(size_t)(ks * 32 + qd * 8 + j) * NYP];
        Are[ks] = a;
    }
    Aim[0] = Are[2];                       // k<64 : Qi
    Aim[1] = Are[3];
    #pragma unroll
    for (int ks = 0; ks < 2; ks++) {       // k>=64: -Qr
        bhalf8 t = Are[ks];
        unsigned* u = (unsigned*)&t;
        #pragma unroll
        for (int j = 0; j < 4; j++) u[j] ^= 0x80008000u;
        Aim[ks + 2] = t;
    }

    f32x4 O[8];
    #pragma unroll
    for (int n = 0; n < 8; n++) O[n] = (f32x4){0.f, 0.f, 0.f, 0.f};
    float Lacc[4] = {0.f, 0.f, 0.f, 0.f};

    int yt0 = (half * 33) / NH, yt1 = ((half + 1) * 33) / NH;

    // ---- K reg-stage source (this lane: chan = w*16 + (lane>>2), 8 y's) ----
    const unsigned short* kb = Pk + ((size_t)bh * 128 + w * 16 + (lane >> 2)) * NYP
                               + (size_t)yt0 * 32 + (lane & 3) * 8;
    int ck3 = w * 2 + (lane >> 5);        // chan>>3 (chunk index)
    int ck7 = (lane >> 2) & 7;            // chan&7  (pos within chunk)
    int rb  = (lane & 3) * 8;             // y base within tile (so y&7 == j)

    // ---- V DMA source: wave w stages rows w*16..w*16+15 (1024 B) ----
    const char* vbase = (const char*)Vt + (size_t)bh * 128 * (NYP * 2);
    const char* vsrc = vbase + ((size_t)(w * 16) + (lane >> 2)) * (NYP * 2)
                       + (size_t)yt0 * 64 + (lane & 3) * 16;

    // swizzled K chunk offsets (ushort units), loop-invariant per lane
    int sw = col & 7;
    int kco[4];
    #pragma unroll
    for (int ks = 0; ks < 4; ks++) kco[ks] = ((ks * 4 + qd) ^ sw) * 8;
    // V chunk unswizzle: stored position of chunk qd in row (n*16+col)
    int vq = (qd ^ ((col >> 2) & 3)) * 8;

    // ---- prologue: stage tile yt0 (K via regs, V via DMA) ----
    uint4 kreg;
    {
        int pb = yt0 & 1;
        kreg = *(const uint4*)kb;  kb += 32;
        GLD16(vsrc, &S.u.kv.Vs[pb][w * 16][0]);  vsrc += 64;
        __builtin_amdgcn_sched_barrier(0);
        asm volatile("s_waitcnt vmcnt(0)" ::: "memory");   // Q + kreg + V done
        __builtin_amdgcn_sched_barrier(0);
        const unsigned short* kv = (const unsigned short*)&kreg;
        #pragma unroll
        for (int j = 0; j < 8; j++)
            S.u.kv.Ks[pb][rb + j][((ck3 ^ j) << 3) | ck7] = kv[j];
        asm volatile("s_waitcnt lgkmcnt(0)" ::: "memory"); // writes drained
        __builtin_amdgcn_sched_barrier(0);
    }

    for (int yt = yt0; yt < yt1; yt++) {
        int cb = yt & 1, nb = cb ^ 1;
        bool has_next = (yt + 1 < yt1);
        if (has_next) {
            kreg = *(const uint4*)kb;  kb += 32;           // next K tile -> regs
            GLD16(vsrc, &S.u.kv.Vs[nb][w * 16][0]);  vsrc += 64;
            __builtin_amdgcn_sched_barrier(0);
            asm volatile("s_waitcnt vmcnt(2)" ::: "memory");  // V[cb] DMA done
        } else {
            __builtin_amdgcn_sched_barrier(0);
            asm volatile("s_waitcnt vmcnt(0)" ::: "memory");
        }
        __builtin_amdgcn_sched_barrier(0);
        __builtin_amdgcn_s_barrier();                      // K[cb]+V[cb] visible
        __builtin_amdgcn_sched_barrier(0);

        const unsigned short* k0 = &S.u.kv.Ks[cb][col][0];
        const unsigned short* k1 = &S.u.kv.Ks[cb][col + 16][0];

        // ---- QK ----
        f32x4 sre[2], sim[2];
        #pragma unroll
        for (int sc = 0; sc < 2; sc++) {
            sre[sc] = (f32x4){0.f, 0.f, 0.f, 0.f};
            sim[sc] = (f32x4){0.f, 0.f, 0.f, 0.f};
        }
        __builtin_amdgcn_s_setprio(1);
        #pragma unroll
        for (int ks = 0; ks < 4; ks++) {
            bhalf8 b0 = *(const bhalf8*)(k0 + kco[ks]);
            bhalf8 b1 = *(const bhalf8*)(k1 + kco[ks]);
            sre[0] = MFMA16(Are[ks], b0, sre[0]);
            sim[0] = MFMA16(Aim[ks], b0, sim[0]);
            sre[1] = MFMA16(Are[ks], b1, sre[1]);
            sim[1] = MFMA16(Aim[ks], b1, sim[1]);
        }
        __builtin_amdgcn_s_setprio(0);

        // ---- p = exp2(sqrt(re^2+im^2))  (0.125*log2e folded into Q) ----
        #pragma unroll
        for (int r = 0; r < 4; r++) {
            float re0 = sre[0][r], im0 = sim[0][r];
            float re1 = sre[1][r], im1 = sim[1][r];
            float s0 = __builtin_amdgcn_sqrtf(fmaf(re0, re0, im0 * im0));
            float s1 = __builtin_amdgcn_sqrtf(fmaf(re1, re1, im1 * im1));
            float p0, p1;
            EXP2F(p0, s0);
            EXP2F(p1, s1);
            Lacc[r] += p0 + p1;
            unsigned up;
            CVTPK(up, p0, p1);
            S.Ps[w][qd * 4 + r][col]      = (unsigned short)up;
            S.Ps[w][qd * 4 + r][col + 16] = (unsigned short)(up >> 16);
        }

        // ---- PV ----
        bhalf8 pa = *(const bhalf8*)&S.Ps[w][col][qd * 8];
        __builtin_amdgcn_s_setprio(1);
        #pragma unroll
        for (int n = 0; n < 8; n++) {
            bhalf8 bv = *(const bhalf8*)&S.u.kv.Vs[cb][n * 16 + col][vq];
            O[n] = MFMA16(pa, bv, O[n]);
        }
        __builtin_amdgcn_s_setprio(0);

        if (has_next) {
            __builtin_amdgcn_sched_barrier(0);
            asm volatile("s_waitcnt vmcnt(1)" ::: "memory");  // kreg landed
            __builtin_amdgcn_sched_barrier(0);
            const unsigned short* kv = (const unsigned short*)&kreg;
            #pragma unroll
            for (int j = 0; j < 8; j++)
                S.u.kv.Ks[nb][rb + j][((ck3 ^ j) << 3) | ck7] = kv[j];
        }
        asm volatile("s_waitcnt lgkmcnt(0)" ::: "memory");    // reads+writes done
        __builtin_amdgcn_sched_barrier(0);
        __builtin_amdgcn_s_barrier();
        __builtin_amdgcn_sched_barrier(0);
    }

    // ---- l reduce + store ----
    #pragma unroll
    for (int r = 0; r < 4; r++) {
        float ls = Lacc[r];
        ls += __shfl_xor(ls, 1);
        ls += __shfl_xor(ls, 2);
        ls += __shfl_xor(ls, 4);
        ls += __shfl_xor(ls, 8);
        if (yt1 == 33) ls -= 31.0f;        // zero-pad columns contributed 1 each
        int x = x0 + w * 16 + qd * 4 + r;
        if (x <= 1024 && col == 0)
            lbuf[((size_t)half * 32 + bh) * NYP + x] = ls;
    }

    // ---- numerator: C-layout -> LDS overlay -> coalesced row writes ----
    const size_t HSZ = (size_t)32 * 128 * NYP;
    unsigned short* nplane = (half < 2 ? nb0 : nb1) + (size_t)(half & 1) * HSZ;

    __syncthreads();                       // Ks/Vs dead; safe to overlay
    #pragma unroll
    for (int n = 0; n < 8; n++) {
        unsigned u0, u1;
        CVTPK(u0, O[n][0], O[n][1]);
        CVTPK(u1, O[n][2], O[n][3]);
        *(unsigned*)&S.u.OutT[n * 16 + col][w * 16 + qd * 4]     = u0;
        *(unsigned*)&S.u.OutT[n * 16 + col][w * 16 + qd * 4 + 2] = u1;
    }
    __syncthreads();
    {
        int kk2 = tid >> 2, seg = tid & 3;
        int xg  = x0 + seg * 32;
        if (xg < NYP) {
            unsigned short* dst = nplane + ((size_t)bh * 128 + kk2) * NYP + xg;
            const unsigned short* srcl = &S.u.OutT[kk2][seg * 32];
            #pragma unroll
            for (int m = 0; m < 4; m++)
                *(uint4*)(dst + m * 8) = *(const uint4*)(srcl + m * 8);
        }
    }
}

// ---------------------------------------------------------------------------
// Inverse rFFT (ortho): combine NH partial planes, 2 series (e, e+1) per
// 128-thread block (wave = series); register-fused build+s0+s1
// (thread m builds kk = {m+64k}); padded radix-4; write st[bh*64+e][2048].
// ---------------------------------------------------------------------------
template<int NH>
__global__ __launch_bounds__(128) void fft_inv(const unsigned short* __restrict__ nb0,
                                               const unsigned short* __restrict__ nb1,
                                               const float2* __restrict__ twg,
                                               const float2* __restrict__ rc,
                                               const float* __restrict__ lbuf,
                                               float* __restrict__ st)
{
    __shared__ float2 buf[2][MMP];
    __shared__ float2 tw[TWP];

    int g  = blockIdx.x;           // series 2g, 2g+1 share bh
    int t  = threadIdx.x;
    int w  = t >> 6, tp = t & 63;
    int q4 = tp >> 4, r = tp & 15;
    int G  = ((tp & 3) << 4) | (tp & 12) | (tp >> 4);   // rev3(tp)

    int sidx = 2 * g + w;
    int e    = sidx & 63;
    int bh   = sidx >> 6;

    #pragma unroll
    for (int i = t; i < 768; i += 128) tw[PAD(i)] = twg[i];

    const size_t HSZ = (size_t)32 * 128 * NYP;
    const unsigned short* pre[NH];
    const unsigned short* pim[NH];
    const float* lb[NH];
    #pragma unroll
    for (int h = 0; h < NH; h++) {
        const unsigned short* base = (h < 2 ? nb0 : nb1) + (size_t)(h & 1) * HSZ;
        pre[h] = base + ((size_t)bh * 128 + e) * NYP;
        pim[h] = base + ((size_t)bh * 128 + 64 + e) * NYP;
        lb[h]  = lbuf + ((size_t)h * 32 + bh) * NYP;
    }

    float2* bufS = buf[w];

    // ---- combine-build + s0 + s1 in registers (kk = tp + 64k) ----
    float2 x[16];
    #pragma unroll
    for (int k = 0; k < 16; k++) {
        int kk = tp + 64 * k;
        int x1 = kk, x2 = 1024 - kk;
        float d1 = 0.f, d2 = 0.f;
        float Axs = 0.f, Ays = 0.f, Bxs = 0.f, Bys = 0.f;
        #pragma unroll
        for (int h = 0; h < NH; h++) {
            d1 += lb[h][x1];
            d2 += lb[h][x2];
            Axs += bf2f(pre[h][x1]);
            Ays += bf2f(pim[h][x1]);
            Bxs += bf2f(pre[h][x2]);
            Bys += bf2f(pim[h][x2]);
        }
        float iv1 = 1.f / d1, iv2 = 1.f / d2;
        float Ax = Axs * iv1, Ay = Ays * iv1;
        float Bx = Bxs * iv2, By = -(Bys * iv2);
        float Ex = 0.5f * (Ax + Bx), Ey = 0.5f * (Ay + By);
        float Dx = 0.5f * (Ax - Bx), Dy = 0.5f * (Ay - By);
        float2 rcv = rc[kk];               // (cos, sin) of +2pi*kk/2048
        float Ox = Dx * rcv.x - Dy * rcv.y;
        float Oy = Dx * rcv.y + Dy * rcv.x;
        x[k] = make_float2(Ex - Oy, Ey + Ox);
    }
    s0s1<false>(x, tw);
    #pragma unroll
    for (int k = 0; k < 16; k++)
        bufS[PAD(16 * G + 4 * (k & 3) + (k >> 2))] = x[k];
    __syncthreads();

    fft_mid<false>(bufS, tw, q4, r);

    float* dst = st + ((size_t)bh * 64 + e) * 2048;
    #pragma unroll
    for (int i = 0; i < 16; i++) {
        int j = tp + 64 * i;
        float2 z = bufS[PAD(j)];
        *(float2*)&dst[2 * j] = make_float2(z.x * INV_SCALE, z.y * INV_SCALE);
    }
}

// ---------------------------------------------------------------------------
// Final transpose: st[bh*64+e][t] -> out[b][t][h][e].  64x64 tiles via LDS.
// ---------------------------------------------------------------------------
__global__ __launch_bounds__(256) void out_tr(const float* __restrict__ st,
                                              float* __restrict__ out)
{
    __shared__ float Ts[64][65];
    int tt  = blockIdx.x;         // t-tile 0..31
    int h   = blockIdx.y;         // 0..7
    int b   = blockIdx.z;         // 0..3
    int tid = threadIdx.x;
    int bh  = b * 8 + h;

    {
        int e = tid >> 2, tc = (tid & 3) * 16;
        const float* src = st + ((size_t)bh * 64 + e) * 2048 + tt * 64 + tc;
        #pragma unroll
        for (int m = 0; m < 4; m++) {
            float4 v4 = *(const float4*)(src + m * 4);
            Ts[e][tc + m * 4 + 0] = v4.x;
            Ts[e][tc + m * 4 + 1] = v4.y;
            Ts[e][tc + m * 4 + 2] = v4.z;
            Ts[e][tc + m * 4 + 3] = v4.w;
        }
    }
    __syncthreads();
    {
        int t = tid >> 2, ec = (tid & 3) * 16;
        float* dst = out + (size_t)b * 2048 * 512 + (size_t)(tt * 64 + t) * 512
                     + h * 64 + ec;
        #pragma unroll
        for (int m = 0; m < 4; m++) {
            float4 v4;
            v4.x = Ts[ec + m * 4 + 0][t];
            v4.y = Ts[ec + m * 4 + 1][t];
            v4.z = Ts[ec + m * 4 + 2][t];
            v4.w = Ts[ec + m * 4 + 3][t];
            *(float4*)(dst + m * 4) = v4;
        }
    }
}

// ---------------------------------------------------------------------------
extern "C" void kernel_launch(void* const* d_in, const int* in_sizes, int n_in,
                              void* d_out, int out_size, void* d_ws, size_t ws_size,
                              hipStream_t stream)
{
    const float* q = (const float*)d_in[0];
    const float* k = (const float*)d_in[1];
    const float* v = (const float*)d_in[2];
    float* out = (float*)d_out;

    char* ws = (char*)d_ws;
    const size_t PL = (size_t)32 * 128 * NYP * sizeof(unsigned short); // 8.65 MB
    unsigned short* Pq = (unsigned short*)(ws);            // live through flash
    unsigned short* Pk = (unsigned short*)(ws + PL);       // live through flash
    unsigned short* Pv = (unsigned short*)(ws + 2 * PL);   // live through flash
    // ttr at 3PL (25.2 MB); dead after fft_fwd, then numb reuses the space.
    unsigned short* ttr = (unsigned short*)(ws + 3 * PL);
    // st aliases Pq/Pk (dead after flash): 16.78 MB <= 2*PL.
    float* st = (float*)(ws);

    const size_t lbuf4 = (size_t)4 * 32 * NYP * sizeof(float);
    const size_t lbuf2 = (size_t)2 * 32 * NYP * sizeof(float);
    const size_t TBL   = (size_t)(768 + 768 + 1025) * sizeof(float2);  // 20.5 KB
    bool big = ws_size >= 7 * PL + lbuf4 + TBL;

    // tables live past every live region in both paths
    char* tb = big ? (ws + 7 * PL + lbuf4) : (ws + 5 * PL + lbuf2);
    float2* twf = (float2*)tb;
    float2* twi = twf + 768;
    float2* rc  = twi + 768;

    hipLaunchKernelGGL(tr_fwd, dim3(32, 8, 12), dim3(256), 0, stream,
                       q, k, v, ttr, twf, twi, rc);
    hipLaunchKernelGGL(fft_fwd, dim3(3 * 1024), dim3(128), 0, stream,
                       ttr, twf, rc, Pq, Pk, Pv);

    if (big) {
        unsigned short* nb0 = (unsigned short*)(ws + 3 * PL);   // planes 0,1
        unsigned short* nb1 = (unsigned short*)(ws + 5 * PL);   // planes 2,3
        float* lbuf = (float*)(ws + 7 * PL);
        hipLaunchKernelGGL((flash_mfma<4>), dim3(9 * 4 * 32), dim3(512), 0, stream,
                           Pq, Pk, Pv, nb0, nb1, lbuf);
        hipLaunchKernelGGL((fft_inv<4>), dim3(1024), dim3(128), 0, stream,
                           nb0, nb1, twi, rc, lbuf, st);
    } else {
        unsigned short* nb0 = (unsigned short*)(ws + 3 * PL);
        float* lbuf = (float*)(ws + 5 * PL);
        hipLaunchKernelGGL((flash_mfma<2>), dim3(9 * 2 * 32), dim3(512), 0, stream,
                           Pq, Pk, Pv, nb0, nb0, lbuf);
        hipLaunchKernelGGL((fft_inv<2>), dim3(1024), dim3(128), 0, stream,
                           nb0, nb0, twi, rc, lbuf, st);
    }

    hipLaunchKernelGGL(out_tr, dim3(32, 8, 4), dim3(256), 0, stream,
                       st, out);
}

// Round 11
// 195.660 us; speedup vs baseline: 1.0437x; 1.0437x over previous
//
#include <hip/hip_runtime.h>
#include <hip/hip_bf16.h>
#include <math.h>

// B=4, L=S=2048, H=8, E=64, T=1.0.  I/O fp32.
// Pipeline: tr_fwd (transpose -> bf16 [tensor,bh,e][t]; first 5 blocks also
// build twiddle/combine tables in ws) -> fft_fwd (real-packed 1024-pt radix-4
// FFT, register-fused stage pairs, 2 series/block, PADded LDS; Q plane
// pre-scaled 0.125*log2e; V plane chunk-swizzled) -> qkpack (K chunks
// XOR-swizzled for linear-LDS DMA) -> flash_mfma (global_load_lds staging,
// LDS dbuf, counted vmcnt(4), raw s_barrier, setprio, cvt_pk, NH=4 y-split)
// -> fft_inv (register-fused; bf16 st) -> out_tr (bf16 st -> fp32 out).
// R19: REVERT R18's in-flash K transpose (8-way ds_write_b16 conflicts,
// 5.29M->9.11M, flash 52->65 us) back to verified R16 structure (197.9), plus
// bf16 st staging (halves fft_inv-write + out_tr-read traffic, 33.6->16.8 MB).
#define LOGN  11
#define NN    2048
#define LOGM  10
#define MM    1024
#define NF    1025
#define NYP   1056         // NF padded to 33 tiles of 32 (pads zeroed)
#define TWO_PI 6.283185307179586f
#define INV_SQRT_N 0.022097086912079608f      // 1/sqrt(2048)
#define INV_SCALE  0.044194173824159216f      // 2/sqrt(2048)  (M*z -> out)
#define LOG2E      1.4426950408889634f

#define PAD(i) ((i) + ((i) >> 4))
#define MMP   1088          // PAD(1023)+1
#define TWP   816           // PAD(767)+1

typedef __attribute__((ext_vector_type(8))) short bhalf8;
typedef __attribute__((ext_vector_type(4))) float f32x4;

#define MFMA16(a, b, c) __builtin_amdgcn_mfma_f32_16x16x32_bf16(a, b, c, 0, 0, 0)

#define GLD16(gp, lp)                                                              \
    __builtin_amdgcn_global_load_lds(                                              \
        (const __attribute__((address_space(1))) void*)(gp),                       \
        (__attribute__((address_space(3))) void*)(lp), 16, 0, 0)

#define CVTPK(dst, lo, hi) \
    asm("v_cvt_pk_bf16_f32 %0, %1, %2" : "=v"(dst) : "v"(lo), "v"(hi))

#define EXP2F(dst, src) \
    asm("v_exp_f32 %0, %1" : "=v"(dst) : "v"(src))

__device__ __forceinline__ unsigned short f2bf(float f) {
    union { float f; unsigned u; } v; v.f = f;
    unsigned r = v.u + 0x7FFFu + ((v.u >> 16) & 1u);   // RNE
    return (unsigned short)(r >> 16);
}
__device__ __forceinline__ float bf2f(unsigned short h) {
    union { unsigned u; float f; } v; v.u = ((unsigned)h) << 16;
    return v.f;
}

__device__ __forceinline__ float2 cmul(float2 x, float2 w) {
    return make_float2(x.x * w.x - x.y * w.y, x.x * w.y + x.y * w.x);
}

// radix-4 butterfly in place (members already twiddled).  fwd: -j on y1.
template<bool FWD>
__device__ __forceinline__ void r4(float2& a, float2& b, float2& c, float2& d) {
    float2 apc = make_float2(a.x + c.x, a.y + c.y);
    float2 amc = make_float2(a.x - c.x, a.y - c.y);
    float2 bpd = make_float2(b.x + d.x, b.y + d.y);
    float2 bmd = make_float2(b.x - d.x, b.y - d.y);
    a = make_float2(apc.x + bpd.x, apc.y + bpd.y);
    c = make_float2(apc.x - bpd.x, apc.y - bpd.y);
    if (FWD) {
        b = make_float2(amc.x + bmd.y, amc.y - bmd.x);
        d = make_float2(amc.x - bmd.y, amc.y + bmd.x);
    } else {
        b = make_float2(amc.x - bmd.y, amc.y + bmd.x);
        d = make_float2(amc.x + bmd.y, amc.y - bmd.x);
    }
}

// s0+s1 on 16 register points x[k], k = 4i+c <-> pos 16G+4c+i.
template<bool FWD>
__device__ __forceinline__ void s0s1(float2 x[16], const float2* tw) {
    #pragma unroll
    for (int c = 0; c < 4; c++)                 // s0: over i, twiddle-free
        r4<FWD>(x[c], x[4 + c], x[8 + c], x[12 + c]);
    #pragma unroll
    for (int i = 0; i < 4; i++) {               // s1: over c, e = 64i
        float2 w1 = tw[PAD(64 * i)], w2 = tw[PAD(128 * i)], w3 = tw[PAD(192 * i)];
        x[4 * i + 1] = cmul(x[4 * i + 1], w1);
        x[4 * i + 2] = cmul(x[4 * i + 2], w2);
        x[4 * i + 3] = cmul(x[4 * i + 3], w3);
        r4<FWD>(x[4 * i], x[4 * i + 1], x[4 * i + 2], x[4 * i + 3]);
    }
}

// s2+s3 fused (one LDS RW) then s4 (one LDS RW).  Thread param (q,r).
// Caller must barrier before (s0s1 writes) — this fn barriers internally.
template<bool FWD>
__device__ __forceinline__ void fft_mid(float2* bufS, const float2* tw, int q, int r)
{
    {   // s2 (e=16r, over c) + s3 (e=4(16c+r), over d)
        float2 v[4][4];   // v[d][c] = buf[256q + 64d + 16c + r]
        #pragma unroll
        for (int d = 0; d < 4; d++)
            #pragma unroll
            for (int c = 0; c < 4; c++)
                v[d][c] = bufS[PAD(256 * q + 64 * d + 16 * c + r)];
        float2 w1 = tw[PAD(16 * r)], w2 = tw[PAD(32 * r)], w3 = tw[PAD(48 * r)];
        #pragma unroll
        for (int d = 0; d < 4; d++) {
            v[d][1] = cmul(v[d][1], w1);
            v[d][2] = cmul(v[d][2], w2);
            v[d][3] = cmul(v[d][3], w3);
            r4<FWD>(v[d][0], v[d][1], v[d][2], v[d][3]);
        }
        #pragma unroll
        for (int c = 0; c < 4; c++) {
            int e = 4 * (16 * c + r);
            float2 u1 = tw[PAD(e)], u2 = tw[PAD(2 * e)], u3 = tw[PAD(3 * e)];
            v[1][c] = cmul(v[1][c], u1);
            v[2][c] = cmul(v[2][c], u2);
            v[3][c] = cmul(v[3][c], u3);
            r4<FWD>(v[0][c], v[1][c], v[2][c], v[3][c]);
        }
        #pragma unroll
        for (int d = 0; d < 4; d++)
            #pragma unroll
            for (int c = 0; c < 4; c++)
                bufS[PAD(256 * q + 64 * d + 16 * c + r)] = v[d][c];
    }
    __syncthreads();
    {   // s4: 4 groups per thread, p4 = 16q + r + 64k, e = p4
        #pragma unroll
        for (int k = 0; k < 4; k++) {
            int p4 = 16 * q + r + 64 * k;
            float2 a = bufS[PAD(p4)];
            float2 b = bufS[PAD(p4 + 256)];
            float2 c = bufS[PAD(p4 + 512)];
            float2 d = bufS[PAD(p4 + 768)];
            b = cmul(b, tw[PAD(p4)]);
            c = cmul(c, tw[PAD(2 * p4)]);
            d = cmul(d, tw[PAD(3 * p4)]);
            r4<FWD>(a, b, c, d);
            bufS[PAD(p4)]       = a;
            bufS[PAD(p4 + 256)] = b;
            bufS[PAD(p4 + 512)] = c;
            bufS[PAD(p4 + 768)] = d;
        }
    }
    __syncthreads();
}

// ---------------------------------------------------------------------------
// Input transpose: in[b][t][h][e] fp32 -> ttr[(tensor*32+bh)*64+e][t] bf16.
// 64x64 tiles via LDS; both global sides fully coalesced; packed u32x2 stores.
// First 5 (y==0,z==0) blocks also build the twiddle/combine tables.
// ---------------------------------------------------------------------------
__global__ __launch_bounds__(256) void tr_fwd(const float* __restrict__ q,
                                              const float* __restrict__ k,
                                              const float* __restrict__ v,
                                              unsigned short* __restrict__ ttr,
                                              float2* __restrict__ twf,
                                              float2* __restrict__ twi,
                                              float2* __restrict__ rc)
{
    __shared__ float Ts[64][65];
    int tt     = blockIdx.x;          // t-tile 0..31
    int h      = blockIdx.y;          // 0..7
    int z      = blockIdx.z;          // tensor*4 + b
    int tensor = z >> 2;
    int b      = z & 3;
    int tid    = threadIdx.x;
    int t0     = tt * 64;

    if (z == 0 && h == 0 && tt < 5) {          // table gen (once per launch)
        int i = tt * 256 + tid;
        if (i < 768) {
            float ang = TWO_PI * (float)i / (float)MM;
            float sv, cv;
            __sincosf(ang, &sv, &cv);
            twf[i] = make_float2(cv, -sv);
            twi[i] = make_float2(cv,  sv);
        }
        if (i < 1025) {
            float ang = TWO_PI * (float)i / (float)NN;
            float sv, cv;
            __sincosf(ang, &sv, &cv);
            rc[i] = make_float2(cv, sv);
        }
    }

    const float* in = (tensor == 0) ? q : (tensor == 1) ? k : v;

    {
        int tl = tid >> 2, ec = (tid & 3) * 16;
        const float* src = in + ((size_t)b * 2048 + t0 + tl) * 512 + h * 64 + ec;
        #pragma unroll
        for (int m = 0; m < 4; m++) {
            float4 v4 = *(const float4*)(src + m * 4);
            Ts[tl][ec + m * 4 + 0] = v4.x;
            Ts[tl][ec + m * 4 + 1] = v4.y;
            Ts[tl][ec + m * 4 + 2] = v4.z;
            Ts[tl][ec + m * 4 + 3] = v4.w;
        }
    }
    __syncthreads();
    {
        int el = tid >> 2, tc = (tid & 3) * 16;
        size_t row = ((size_t)(tensor * 32 + b * 8 + h)) * 64 + el;
        unsigned short* dst = ttr + row * 2048 + t0 + tc;
        #pragma unroll
        for (int m = 0; m < 4; m++) {
            float a0 = Ts[tc + m * 4 + 0][el], a1 = Ts[tc + m * 4 + 1][el];
            float a2 = Ts[tc + m * 4 + 2][el], a3 = Ts[tc + m * 4 + 3][el];
            unsigned u0, u1;
            CVTPK(u0, a0, a1);
            CVTPK(u1, a2, a3);
            uint2 o; o.x = u0; o.y = u1;
            *(uint2*)(dst + m * 4) = o;
        }
    }
}

// ---------------------------------------------------------------------------
// Forward rFFT (ortho), 2 series per 128-thread block (wave = series).
// Register-fused load+s0+s1; thread m loads inputs {m+64k} (coalesced).
// Output bf16 planes P[bh*128+kk][1056]; Q plane carries 0.125*log2e.
// V plane: 8-elem chunks stored at chunk ^ ((row>>2)&3).
// ---------------------------------------------------------------------------
__global__ __launch_bounds__(128) void fft_fwd(const unsigned short* __restrict__ ttr,
                                               const float2* __restrict__ twg,
                                               const float2* __restrict__ rc,
                                               unsigned short* __restrict__ Pq,
                                               unsigned short* __restrict__ Pk,
                                               unsigned short* __restrict__ Pv)
{
    __shared__ float2 buf[2][MMP];
    __shared__ float2 tw[TWP];

    int g  = blockIdx.x;              // 0..3071
    int t  = threadIdx.x;
    int w  = t >> 6, tp = t & 63;
    int q4 = tp >> 4, r = tp & 15;
    int G  = ((tp & 3) << 4) | (tp & 12) | (tp >> 4);   // rev3(tp)

    int s      = 2 * g + w;
    int p      = s % 96;              // tensor*32 + bh
    int e      = s / 96;              // 0..63
    int tensor = p / 32;
    int bh     = p % 32;

    unsigned short* plane = (tensor == 0) ? Pq : (tensor == 1) ? Pk : Pv;
    float scl = (tensor == 0) ? (INV_SQRT_N * 0.125f * LOG2E) : INV_SQRT_N;
    int vk3 = (tensor == 2) ? (((e >> 2) & 3) << 3) : 0;
    unsigned short* dre  = plane + ((size_t)bh * 128 + e) * NYP;
    unsigned short* dim_ = dre + (size_t)64 * NYP;
    const unsigned short* src = ttr + ((size_t)p * 64 + e) * 2048;

    #pragma unroll
    for (int i = t; i < 768; i += 128) tw[PAD(i)] = twg[i];

    float2* bufS = buf[w];

    // ---- load + s0 + s1 in registers ----
    float2 x[16];
    #pragma unroll
    for (int k = 0; k < 16; k++) {
        unsigned pr = *(const unsigned*)(src + 2 * (tp + 64 * k));
        x[k] = make_float2(bf2f((unsigned short)(pr & 0xFFFFu)),
                           bf2f((unsigned short)(pr >> 16)));
    }
    s0s1<true>(x, tw);
    #pragma unroll
    for (int k = 0; k < 16; k++)
        bufS[PAD(16 * G + 4 * (k & 3) + (k >> 2))] = x[k];
    __syncthreads();

    fft_mid<true>(bufS, tw, q4, r);

    // fwd combine uses (cs,sn) = (rc.x, -rc.y):
#define RPOINT(Ai, Bi, CX, CY, XR, XI) do {                                \
        float Ex = 0.5f * (Ai.x + Bi.x), Ey = 0.5f * (Ai.y - Bi.y);        \
        float Dx = 0.5f * (Ai.x - Bi.x), Dy = 0.5f * (Ai.y + Bi.y);        \
        float Ox = Dy, Oy = -Dx;                                           \
        XR = (Ex + (CX) * Ox + (CY) * Oy) * scl;                           \
        XI = (Ey + (CX) * Oy - (CY) * Ox) * scl;                           \
    } while (0)

    #pragma unroll
    for (int i = 0; i < 8; i++) {
        int kk = 2 * tp + 128 * i;                   // even, 0..1022
        float2 A0 = bufS[PAD(kk)];
        float2 B0 = bufS[PAD((MM - kk) & (MM - 1))];
        float2 A1 = bufS[PAD(kk + 1)];
        float2 B1 = bufS[PAD(MM - kk - 1)];
        float4 rq = *(const float4*)(&rc[kk]);       // (c0,s0,c1,s1)
        float Xr0, Xi0, Xr1, Xi1;
        RPOINT(A0, B0, rq.x, rq.y, Xr0, Xi0);
        RPOINT(A1, B1, rq.z, rq.w, Xr1, Xi1);
        unsigned ur, ui;
        CVTPK(ur, Xr0, Xr1);
        CVTPK(ui, Xi0, Xi1);
        int ks = kk ^ vk3;                           // swizzle stays even
        *(unsigned*)(dre + ks)  = ur;
        *(unsigned*)(dim_ + ks) = ui;
    }
    // tail: kk = 1024 (cs=-1, sn=0) + zero pads 1025..1055
    if (tp < 16) {
        unsigned ur = 0, ui = 0;
        if (tp == 0) {
            float2 A = bufS[PAD(0)];                  // A == Bc at kk=1024
            float Xr = (A.x - A.y) * scl;             // Ex + (-1)*Ox
            float zz = 0.f;
            CVTPK(ur, Xr, zz);
        }
        int ks = (1024 + 2 * tp) ^ vk3;
        *(unsigned*)(dre + ks)  = ur;
        *(unsigned*)(dim_ + ks) = ui;
    }
#undef RPOINT
}

// ---------------------------------------------------------------------------
// Transpose q,k planes [bh*128+kk][1056] -> [bh][1056][128].
// K rows are written with 16B chunks XOR-swizzled (chunk ^ (y&7)) so flash can
// DMA them linearly into LDS and still read bank-conflict-free (rule #21).
// ---------------------------------------------------------------------------
__global__ __launch_bounds__(256) void qkpack(const unsigned short* __restrict__ Pq,
                                              const unsigned short* __restrict__ Pk,
                                              unsigned short* __restrict__ Qp,
                                              unsigned short* __restrict__ Kp)
{
    __shared__ unsigned short Ts[32][136];
    int y0  = blockIdx.x * 32;
    int bh  = blockIdx.y;
    int tsr = blockIdx.z;
    int tid = threadIdx.x;

    const unsigned short* srcp = (tsr == 0) ? Pq : Pk;
    unsigned short* dstp       = (tsr == 0) ? Qp : Kp;

    {
        int kk = tid >> 1, seg = tid & 1;
        const unsigned short* sp = srcp + ((size_t)bh * 128 + kk) * NYP + y0 + seg * 16;
        uint4 va = *(const uint4*)sp;
        uint4 vb = *(const uint4*)(sp + 8);
        const unsigned short* pa = (const unsigned short*)&va;
        const unsigned short* pb = (const unsigned short*)&vb;
        #pragma unroll
        for (int j = 0; j < 8; j++) Ts[seg * 16 + j][kk] = pa[j];
        #pragma unroll
        for (int j = 0; j < 8; j++) Ts[seg * 16 + 8 + j][kk] = pb[j];
    }
    __syncthreads();
    {
        int y = tid >> 3, c = tid & 7;       // c: 32B pair (chunks 2c, 2c+1)
        uint4 lo = *(const uint4*)&Ts[y][c * 16];
        uint4 hi = *(const uint4*)&Ts[y][c * 16 + 8];
        char* rowb = (char*)(dstp + ((size_t)bh * NYP + y0 + y) * 128);
        if (tsr == 0) {
            *(uint4*)(rowb + c * 32)      = lo;
            *(uint4*)(rowb + c * 32 + 16) = hi;
        } else {
            int s = y & 7;
            *(uint4*)(rowb + (((2 * c)     ^ s) << 4)) = lo;
            *(uint4*)(rowb + (((2 * c + 1) ^ s) << 4)) = hi;
        }
    }
}

// ---------------------------------------------------------------------------
// MFMA flash attention, no-max softmax, y-split xNH, XCD swizzle.
// K/V staged via global_load_lds into LDS double-buffer; counted vmcnt(4)
// keeps next-tile loads in flight across raw s_barriers (T3/T4); setprio (T5).
// numb partial planes: [h][bh][kk=0..127][x=0..1055] bf16; planes 0,1 at nb0,
// planes 2,3 at nb1 (two disjoint ws regions).
// ---------------------------------------------------------------------------
struct FlashShared {
    union {
        struct {
            unsigned short Ks[2][32][128];   // 16 KB, chunk-XOR-swizzled rows
            unsigned short Vs[2][128][32];   // 16 KB, chunk-swizzled (fft_fwd)
        } kv;                                // 32 KB
        unsigned short OutT[128][72];        // 18 KB (epilogue only)
    } u;
    unsigned short Ps[4][16][40];            // 5 KB, wave-private
};

template<int NH>
__global__ __launch_bounds__(256) void flash_mfma(
    const unsigned short* __restrict__ Qp,   // [bh][1056][128] bf16 (scaled)
    const unsigned short* __restrict__ Kp,   // [bh][1056][128] bf16, swizzled
    const unsigned short* __restrict__ Vt,   // [bh*128+kk][1056] bf16, swizzled
    unsigned short* __restrict__ nb0,        // partial planes 0,1
    unsigned short* __restrict__ nb1,        // partial planes 2,3 (NH=4)
    float* __restrict__ lbuf)                // [NH][bh*1056+x] fp32
{
    __shared__ FlashShared S;

    int g    = blockIdx.x;            // idx*32 + bh : g%8 == bh%8 (XCD pin)
    int bh   = g & 31;
    int idx  = g >> 5;                // 0..17*NH-1
    int half = idx / 17;              // y-quarter (or y-half)
    int x0   = (idx % 17) * 64;
    int tid  = threadIdx.x;
    int w    = tid >> 6;
    int lane = tid & 63;
    int qd   = lane >> 4;
    int col  = lane & 15;

    // ---- Q A-fragments: direct bf16 loads + sign trick ----
    int xrow = x0 + w * 16 + col;
    int xq   = min(xrow, 1024);
    const unsigned short* qb = Qp + ((size_t)bh * NYP + xq) * 128 + qd * 8;
    bhalf8 Are[4], Aim[4];
    #pragma unroll
    for (int ks = 0; ks < 4; ks++) Are[ks] = *(const bhalf8*)(qb + ks * 32);
    Aim[0] = Are[2];                       // k<64 : Qi
    Aim[1] = Are[3];
    #pragma unroll
    for (int ks = 0; ks < 2; ks++) {       // k>=64: -Qr
        bhalf8 t = Are[ks];
        unsigned* u = (unsigned*)&t;
        #pragma unroll
        for (int j = 0; j < 4; j++) u[j] ^= 0x80008000u;
        Aim[ks + 2] = t;
    }

    f32x4 O[8];
    #pragma unroll
    for (int n = 0; n < 8; n++) O[n] = (f32x4){0.f, 0.f, 0.f, 0.f};
    float Lacc[4] = {0.f, 0.f, 0.f, 0.f};

    int yt0 = (half * 33) / NH, yt1 = ((half + 1) * 33) / NH;

    // ---- per-wave DMA source pointers (bytes) ----
    const char* ksrc = (const char*)Kp
        + ((size_t)bh * NYP + (size_t)yt0 * 32 + w * 8) * 256 + lane * 16;
    const char* vbase = (const char*)Vt + (size_t)bh * 128 * (NYP * 2);
    const char* vsrc0 = vbase + ((size_t)(w * 32) + (lane >> 2)) * (NYP * 2)
                        + (size_t)yt0 * 64 + (lane & 3) * 16;
    const char* vsrc1 = vsrc0 + (size_t)16 * (NYP * 2);

    // swizzled K chunk offsets (ushort units), loop-invariant per lane
    int sw = col & 7;
    int kco[4];
    #pragma unroll
    for (int ks = 0; ks < 4; ks++) kco[ks] = ((ks * 4 + qd) ^ sw) * 8;
    // V chunk unswizzle: stored position of chunk qd in row (n*16+col)
    int vq = (qd ^ ((col >> 2) & 3)) * 8;

    // ---- prologue: stage tile yt0 ----
    {
        int pb = yt0 & 1;
        GLD16(ksrc,         &S.u.kv.Ks[pb][w * 8][0]);
        GLD16(ksrc + 1024,  &S.u.kv.Ks[pb][w * 8 + 4][0]);
        GLD16(vsrc0,        &S.u.kv.Vs[pb][w * 32][0]);
        GLD16(vsrc1,        &S.u.kv.Vs[pb][w * 32 + 16][0]);
        ksrc += 8192; vsrc0 += 64; vsrc1 += 64;
    }

    for (int yt = yt0; yt < yt1; yt++) {
        int cb = yt & 1, nb = cb ^ 1;
        if (yt + 1 < yt1) {
            // issue next tile's DMA (stays in flight across both barriers)
            GLD16(ksrc,         &S.u.kv.Ks[nb][w * 8][0]);
            GLD16(ksrc + 1024,  &S.u.kv.Ks[nb][w * 8 + 4][0]);
            GLD16(vsrc0,        &S.u.kv.Vs[nb][w * 32][0]);
            GLD16(vsrc1,        &S.u.kv.Vs[nb][w * 32 + 16][0]);
            ksrc += 8192; vsrc0 += 64; vsrc1 += 64;
            __builtin_amdgcn_sched_barrier(0);
            asm volatile("s_waitcnt vmcnt(4)" ::: "memory");   // cur tile done
        } else {
            __builtin_amdgcn_sched_barrier(0);
            asm volatile("s_waitcnt vmcnt(0)" ::: "memory");
        }
        __builtin_amdgcn_sched_barrier(0);
        __builtin_amdgcn_s_barrier();                          // all waves' DMA visible
        __builtin_amdgcn_sched_barrier(0);

        const unsigned short* k0 = &S.u.kv.Ks[cb][col][0];
        const unsigned short* k1 = &S.u.kv.Ks[cb][col + 16][0];

        // ---- QK ----
        f32x4 sre[2], sim[2];
        #pragma unroll
        for (int sc = 0; sc < 2; sc++) {
            sre[sc] = (f32x4){0.f, 0.f, 0.f, 0.f};
            sim[sc] = (f32x4){0.f, 0.f, 0.f, 0.f};
        }
        __builtin_amdgcn_s_setprio(1);
        #pragma unroll
        for (int ks = 0; ks < 4; ks++) {
            bhalf8 b0 = *(const bhalf8*)(k0 + kco[ks]);
            bhalf8 b1 = *(const bhalf8*)(k1 + kco[ks]);
            sre[0] = MFMA16(Are[ks], b0, sre[0]);
            sim[0] = MFMA16(Aim[ks], b0, sim[0]);
            sre[1] = MFMA16(Are[ks], b1, sre[1]);
            sim[1] = MFMA16(Aim[ks], b1, sim[1]);
        }
        __builtin_amdgcn_s_setprio(0);

        // ---- p = exp2(sqrt(re^2+im^2))  (0.125*log2e folded into Q) ----
        #pragma unroll
        for (int r = 0; r < 4; r++) {
            float re0 = sre[0][r], im0 = sim[0][r];
            float re1 = sre[1][r], im1 = sim[1][r];
            float s0 = __builtin_amdgcn_sqrtf(fmaf(re0, re0, im0 * im0));
            float s1 = __builtin_amdgcn_sqrtf(fmaf(re1, re1, im1 * im1));
            float p0, p1;
            EXP2F(p0, s0);
            EXP2F(p1, s1);
            Lacc[r] += p0 + p1;
            unsigned up;
            CVTPK(up, p0, p1);
            S.Ps[w][qd * 4 + r][col]      = (unsigned short)up;
            S.Ps[w][qd * 4 + r][col + 16] = (unsigned short)(up >> 16);
        }

        // ---- PV ----
        bhalf8 pa = *(const bhalf8*)&S.Ps[w][col][qd * 8];
        __builtin_amdgcn_s_setprio(1);
        #pragma unroll
        for (int n = 0; n < 8; n++) {
            bhalf8 bv = *(const bhalf8*)&S.u.kv.Vs[cb][n * 16 + col][vq];
            O[n] = MFMA16(pa, bv, O[n]);
        }
        __builtin_amdgcn_s_setprio(0);

        asm volatile("s_waitcnt lgkmcnt(0)" ::: "memory");     // reads retired
        __builtin_amdgcn_sched_barrier(0);
        __builtin_amdgcn_s_barrier();                          // safe to overwrite cb^1
        __builtin_amdgcn_sched_barrier(0);
    }

    // ---- l reduce + store ----
    #pragma unroll
    for (int r = 0; r < 4; r++) {
        float ls = Lacc[r];
        ls += __shfl_xor(ls, 1);
        ls += __shfl_xor(ls, 2);
        ls += __shfl_xor(ls, 4);
        ls += __shfl_xor(ls, 8);
        if (yt1 == 33) ls -= 31.0f;        // zero-pad columns contributed 1 each
        int x = x0 + w * 16 + qd * 4 + r;
        if (x <= 1024 && col == 0)
            lbuf[((size_t)half * 32 + bh) * NYP + x] = ls;
    }

    // ---- numerator: C-layout -> LDS overlay -> coalesced row writes ----
    const size_t HSZ = (size_t)32 * 128 * NYP;
    unsigned short* nplane = (half < 2 ? nb0 : nb1) + (size_t)(half & 1) * HSZ;

    __syncthreads();                       // Ks/Vs dead; safe to overlay
    #pragma unroll
    for (int n = 0; n < 8; n++) {
        unsigned u0, u1;
        CVTPK(u0, O[n][0], O[n][1]);
        CVTPK(u1, O[n][2], O[n][3]);
        *(unsigned*)&S.u.OutT[n * 16 + col][w * 16 + qd * 4]     = u0;
        *(unsigned*)&S.u.OutT[n * 16 + col][w * 16 + qd * 4 + 2] = u1;
    }
    __syncthreads();
    {
        int kk2 = tid >> 1, seg = tid & 1;
        int xg  = x0 + seg * 32;
        if (xg < NYP) {
            unsigned short* dst = nplane + ((size_t)bh * 128 + kk2) * NYP + xg;
            const unsigned short* srcl = &S.u.OutT[kk2][seg * 32];
            #pragma unroll
            for (int m = 0; m < 4; m++)
                *(uint4*)(dst + m * 8) = *(const uint4*)(srcl + m * 8);
        }
    }
}

// ---------------------------------------------------------------------------
// Inverse rFFT (ortho): combine NH partial planes, 2 series (e, e+1) per
// 128-thread block (wave = series); register-fused build+s0+s1
// (thread m builds kk = {m+64k}); padded radix-4; write bf16 st.
// ---------------------------------------------------------------------------
template<int NH>
__global__ __launch_bounds__(128) void fft_inv(const unsigned short* __restrict__ nb0,
                                               const unsigned short* __restrict__ nb1,
                                               const float2* __restrict__ twg,
                                               const float2* __restrict__ rc,
                                               const float* __restrict__ lbuf,
                                               unsigned short* __restrict__ st)
{
    __shared__ float2 buf[2][MMP];
    __shared__ float2 tw[TWP];

    int g  = blockIdx.x;           // series 2g, 2g+1 share bh
    int t  = threadIdx.x;
    int w  = t >> 6, tp = t & 63;
    int q4 = tp >> 4, r = tp & 15;
    int G  = ((tp & 3) << 4) | (tp & 12) | (tp >> 4);   // rev3(tp)

    int sidx = 2 * g + w;
    int e    = sidx & 63;
    int bh   = sidx >> 6;

    #pragma unroll
    for (int i = t; i < 768; i += 128) tw[PAD(i)] = twg[i];

    const size_t HSZ = (size_t)32 * 128 * NYP;
    const unsigned short* pre[NH];
    const unsigned short* pim[NH];
    const float* lb[NH];
    #pragma unroll
    for (int h = 0; h < NH; h++) {
        const unsigned short* base = (h < 2 ? nb0 : nb1) + (size_t)(h & 1) * HSZ;
        pre[h] = base + ((size_t)bh * 128 + e) * NYP;
        pim[h] = base + ((size_t)bh * 128 + 64 + e) * NYP;
        lb[h]  = lbuf + ((size_t)h * 32 + bh) * NYP;
    }

    float2* bufS = buf[w];

    // ---- combine-build + s0 + s1 in registers (kk = tp + 64k) ----
    float2 x[16];
    #pragma unroll
    for (int k = 0; k < 16; k++) {
        int kk = tp + 64 * k;
        int x1 = kk, x2 = 1024 - kk;
        float d1 = 0.f, d2 = 0.f;
        float Axs = 0.f, Ays = 0.f, Bxs = 0.f, Bys = 0.f;
        #pragma unroll
        for (int h = 0; h < NH; h++) {
            d1 += lb[h][x1];
            d2 += lb[h][x2];
            Axs += bf2f(pre[h][x1]);
            Ays += bf2f(pim[h][x1]);
            Bxs += bf2f(pre[h][x2]);
            Bys += bf2f(pim[h][x2]);
        }
        float iv1 = 1.f / d1, iv2 = 1.f / d2;
        float Ax = Axs * iv1, Ay = Ays * iv1;
        float Bx = Bxs * iv2, By = -(Bys * iv2);
        float Ex = 0.5f * (Ax + Bx), Ey = 0.5f * (Ay + By);
        float Dx = 0.5f * (Ax - Bx), Dy = 0.5f * (Ay - By);
        float2 rcv = rc[kk];               // (cos, sin) of +2pi*kk/2048
        float Ox = Dx * rcv.x - Dy * rcv.y;
        float Oy = Dx * rcv.y + Dy * rcv.x;
        x[k] = make_float2(Ex - Oy, Ey + Ox);
    }
    s0s1<false>(x, tw);
    #pragma unroll
    for (int k = 0; k < 16; k++)
        bufS[PAD(16 * G + 4 * (k & 3) + (k >> 2))] = x[k];
    __syncthreads();

    fft_mid<false>(bufS, tw, q4, r);

    unsigned short* dst = st + ((size_t)bh * 64 + e) * 2048;
    #pragma unroll
    for (int i = 0; i < 16; i++) {
        int j = tp + 64 * i;
        float2 z = bufS[PAD(j)];
        unsigned u;
        CVTPK(u, z.x * INV_SCALE, z.y * INV_SCALE);
        *(unsigned*)(dst + 2 * j) = u;
    }
}

// ---------------------------------------------------------------------------
// Final transpose: st[bh*64+e][t] bf16 -> out[b][t][h][e] fp32.
// 64x64 tiles via LDS (tile kept fp32 so bank behavior is unchanged).
// ---------------------------------------------------------------------------
__global__ __launch_bounds__(256) void out_tr(const unsigned short* __restrict__ st,
                                              float* __restrict__ out)
{
    __shared__ float Ts[64][65];
    int tt  = blockIdx.x;         // t-tile 0..31
    int h   = blockIdx.y;         // 0..7
    int b   = blockIdx.z;         // 0..3
    int tid = threadIdx.x;
    int bh  = b * 8 + h;

    {
        int e = tid >> 2, tc = (tid & 3) * 16;
        const unsigned short* src = st + ((size_t)bh * 64 + e) * 2048 + tt * 64 + tc;
        uint4 va = *(const uint4*)src;
        uint4 vb = *(const uint4*)(src + 8);
        const unsigned short* pa = (const unsigned short*)&va;
        const unsigned short* pb = (const unsigned short*)&vb;
        #pragma unroll
        for (int j = 0; j < 8; j++) Ts[e][tc + j] = bf2f(pa[j]);
        #pragma unroll
        for (int j = 0; j < 8; j++) Ts[e][tc + 8 + j] = bf2f(pb[j]);
    }
    __syncthreads();
    {
        int t = tid >> 2, ec = (tid & 3) * 16;
        float* dst = out + (size_t)b * 2048 * 512 + (size_t)(tt * 64 + t) * 512
                     + h * 64 + ec;
        #pragma unroll
        for (int m = 0; m < 4; m++) {
            float4 v4;
            v4.x = Ts[ec + m * 4 + 0][t];
            v4.y = Ts[ec + m * 4 + 1][t];
            v4.z = Ts[ec + m * 4 + 2][t];
            v4.w = Ts[ec + m * 4 + 3][t];
            *(float4*)(dst + m * 4) = v4;
        }
    }
}

// ---------------------------------------------------------------------------
extern "C" void kernel_launch(void* const* d_in, const int* in_sizes, int n_in,
                              void* d_out, int out_size, void* d_ws, size_t ws_size,
                              hipStream_t stream)
{
    const float* q = (const float*)d_in[0];
    const float* k = (const float*)d_in[1];
    const float* v = (const float*)d_in[2];
    float* out = (float*)d_out;

    char* ws = (char*)d_ws;
    const size_t PL = (size_t)32 * 128 * NYP * sizeof(unsigned short); // 8.65 MB
    unsigned short* Pq = (unsigned short*)(ws);
    unsigned short* Pk = (unsigned short*)(ws + PL);
    unsigned short* Pv = (unsigned short*)(ws + 2 * PL);
    // ttr at 3PL (25.2 MB); dead after fft_fwd, then Qp/Kp reuse the space.
    unsigned short* ttr = (unsigned short*)(ws + 3 * PL);
    unsigned short* Qp = (unsigned short*)(ws + 3 * PL);
    unsigned short* Kp = (unsigned short*)(ws + 4 * PL);
    // st (bf16, 8.39 MB) aliases Qp (dead after flash_mfma).
    unsigned short* st = (unsigned short*)(ws + 3 * PL);

    const size_t lbuf4 = (size_t)4 * 32 * NYP * sizeof(float);
    const size_t lbuf2 = (size_t)2 * 32 * NYP * sizeof(float);
    const size_t TBL   = (size_t)(768 + 768 + 1025) * sizeof(float2);  // 20.5 KB
    bool big = ws_size >= 7 * PL + lbuf4 + TBL;

    // tables live past every live region in both paths
    char* tb = big ? (ws + 7 * PL + lbuf4) : (ws + 5 * PL + lbuf2);
    float2* twf = (float2*)tb;
    float2* twi = twf + 768;
    float2* rc  = twi + 768;

    hipLaunchKernelGGL(tr_fwd, dim3(32, 8, 12), dim3(256), 0, stream,
                       q, k, v, ttr, twf, twi, rc);
    hipLaunchKernelGGL(fft_fwd, dim3(3 * 1024), dim3(128), 0, stream,
                       ttr, twf, rc, Pq, Pk, Pv);
    hipLaunchKernelGGL(qkpack, dim3(33, 32, 2), dim3(256), 0, stream,
                       Pq, Pk, Qp, Kp);

    if (big) {
        unsigned short* nb0 = (unsigned short*)(ws);
        unsigned short* nb1 = (unsigned short*)(ws + 5 * PL);
        float* lbuf = (float*)(ws + 7 * PL);
        hipLaunchKernelGGL((flash_mfma<4>), dim3(17 * 4 * 32), dim3(256), 0, stream,
                           Qp, Kp, Pv, nb0, nb1, lbuf);
        hipLaunchKernelGGL((fft_inv<4>), dim3(1024), dim3(128), 0, stream,
                           nb0, nb1, twi, rc, lbuf, st);
    } else {
        unsigned short* nb0 = (unsigned short*)(ws);
        float* lbuf = (float*)(ws + 5 * PL);
        hipLaunchKernelGGL((flash_mfma<2>), dim3(17 * 2 * 32), dim3(256), 0, stream,
                           Qp, Kp, Pv, nb0, nb0, lbuf);
        hipLaunchKernelGGL((fft_inv<2>), dim3(1024), dim3(128), 0, stream,
                           nb0, nb0, twi, rc, lbuf, st);
    }

    hipLaunchKernelGGL(out_tr, dim3(32, 8, 4), dim3(256), 0, stream,
                       st, out);
}